// Round 1
// baseline (128.993 us; speedup 1.0000x reference)
//
#include <hip/hip_runtime.h>
#include <hip/hip_bf16.h>

#define NROWS 8192
#define KDIM  512
#define NT    64                 // 8192/128 tiles per dim
#define NBLK  (NT*(NT+1)/2)      // upper-triangle tile pairs = 2080

typedef __attribute__((ext_vector_type(8))) short bf16x8;
typedef __attribute__((ext_vector_type(4))) float f32x4;

__device__ __forceinline__ void async_copy16(const void* g, void* l) {
    __builtin_amdgcn_global_load_lds((const __attribute__((address_space(1))) void*)g,
                                     (__attribute__((address_space(3))) void*)l,
                                     16, 0, 0);
}

// Convert z (fp32) -> bf16 into workspace, compute sq[i] = ||z_i||^2 in fp32,
// and zero the global accumulator. One wave per row.
__global__ __launch_bounds__(256) void prep_kernel(const float* __restrict__ z,
                                                   unsigned short* __restrict__ zb,
                                                   float* __restrict__ sq,
                                                   float* __restrict__ acc) {
    int wave = threadIdx.x >> 6, lane = threadIdx.x & 63;
    int row = blockIdx.x * 4 + wave;
    const float* zr = z + (size_t)row * KDIM + lane * 8;
    float4 v0 = *(const float4*)zr;
    float4 v1 = *(const float4*)(zr + 4);
    float vals[8] = {v0.x, v0.y, v0.z, v0.w, v1.x, v1.y, v1.z, v1.w};
    union { __hip_bfloat16 h[8]; uint4 u; } p;
    float s = 0.f;
#pragma unroll
    for (int i = 0; i < 8; ++i) { s += vals[i] * vals[i]; p.h[i] = __float2bfloat16(vals[i]); }
    *(uint4*)(zb + (size_t)row * KDIM + lane * 8) = p.u;
#pragma unroll
    for (int off = 32; off; off >>= 1) s += __shfl_down(s, off);
    if (lane == 0) sq[row] = s;
    if (blockIdx.x == 0 && threadIdx.x == 0) acc[0] = 0.f;
}

// One 128x128 tile of the Gram matrix per block (upper triangle only),
// fused exp epilogue + block reduction -> one atomicAdd per block.
__global__ __launch_bounds__(256) void gram_kernel(const unsigned short* __restrict__ zb,
                                                   const float* __restrict__ sq,
                                                   float* __restrict__ acc) {
    __shared__ unsigned short Ash[128 * 64];   // 16 KB
    __shared__ unsigned short Bsh[128 * 64];   // 16 KB

    int tid = threadIdx.x;
    int wave = tid >> 6, lane = tid & 63;
    int quad = lane >> 4, r = lane & 15;
    int wm = wave >> 1, wn = wave & 1;

    // linear block id -> (bi, bj) with bi <= bj
    int rem = blockIdx.x, bi = 0;
    while (rem >= NT - bi) { rem -= NT - bi; ++bi; }
    int bj = bi + rem;

    const unsigned short* Ag = zb + (size_t)bi * 128 * KDIM;
    const unsigned short* Bg = zb + (size_t)bj * 128 * KDIM;

    f32x4 zero = {0.f, 0.f, 0.f, 0.f};
    f32x4 accf[4][4];
#pragma unroll
    for (int mi = 0; mi < 4; ++mi)
#pragma unroll
        for (int ni = 0; ni < 4; ++ni) accf[mi][ni] = zero;

    int swz = r & 7;  // (row & 7) for every fragment row this lane touches

    for (int k0 = 0; k0 < KDIM; k0 += 64) {
        // ---- global -> LDS staging, 16B per lane, XOR-swizzled k-chunks ----
#pragma unroll
        for (int it = 0; it < 4; ++it) {
            int c = it * 256 + tid;
            int row = c >> 3, cc = c & 7;
            int sc = cc ^ (row & 7);   // source chunk (swizzle on global side)
            const unsigned short* srcA = Ag + (size_t)row * KDIM + k0 + sc * 8;
            const unsigned short* srcB = Bg + (size_t)row * KDIM + k0 + sc * 8;
            async_copy16(srcA, (char*)Ash + c * 16);
            async_copy16(srcB, (char*)Bsh + c * 16);
        }
        __syncthreads();

        // ---- MFMA over BK=64 (two K=32 steps) ----
#pragma unroll
        for (int kh = 0; kh < 2; ++kh) {
            bf16x8 af[4], bfr[4];
            int kc = kh * 4 + quad;   // logical 8-elem chunk index within BK
#pragma unroll
            for (int mi = 0; mi < 4; ++mi) {
                int row = wm * 64 + mi * 16 + r;
                af[mi] = *(const bf16x8*)(Ash + row * 64 + ((kc ^ swz) * 8));
            }
#pragma unroll
            for (int ni = 0; ni < 4; ++ni) {
                int row = wn * 64 + ni * 16 + r;
                bfr[ni] = *(const bf16x8*)(Bsh + row * 64 + ((kc ^ swz) * 8));
            }
#pragma unroll
            for (int mi = 0; mi < 4; ++mi)
#pragma unroll
                for (int ni = 0; ni < 4; ++ni)
                    accf[mi][ni] = __builtin_amdgcn_mfma_f32_16x16x32_bf16(
                        af[mi], bfr[ni], accf[mi][ni], 0, 0, 0);
        }
        __syncthreads();
    }

    // ---- fused epilogue: exp(-D/tau) for gi<gj, local sum ----
    int rowBase = bi * 128 + wm * 64;
    int colBase = bj * 128 + wn * 64;
    float sqj[4];
#pragma unroll
    for (int ni = 0; ni < 4; ++ni) sqj[ni] = sq[colBase + ni * 16 + r];

    float local = 0.f;
#pragma unroll
    for (int mi = 0; mi < 4; ++mi) {
#pragma unroll
        for (int rr = 0; rr < 4; ++rr) {
            int gi = rowBase + mi * 16 + quad * 4 + rr;   // C row = quad*4 + reg
            float sqi = sq[gi];
#pragma unroll
            for (int ni = 0; ni < 4; ++ni) {
                int gj = colBase + ni * 16 + r;           // C col = lane & 15
                float d = sqi + sqj[ni] - 2.f * accf[mi][ni][rr];
                d = fmaxf(d, 0.f);
                float e = __expf(d * (-1.f / 100.f));
                local += (gi < gj) ? e : 0.f;
            }
        }
    }

    // wave -> block -> global reduction
#pragma unroll
    for (int off = 32; off; off >>= 1) local += __shfl_down(local, off);
    __shared__ float wsum[4];
    if (lane == 0) wsum[wave] = local;
    __syncthreads();
    if (tid == 0) atomicAdd(acc, wsum[0] + wsum[1] + wsum[2] + wsum[3]);
}

__global__ void finish_kernel(const float* __restrict__ acc, float* __restrict__ out) {
    float total = 2.f * acc[0];   // triangle sum counted once -> double it
    out[0] = logf(total / ((float)NROWS * (float)(NROWS - 1)));
}

extern "C" void kernel_launch(void* const* d_in, const int* in_sizes, int n_in,
                              void* d_out, int out_size, void* d_ws, size_t ws_size,
                              hipStream_t stream) {
    const float* z = (const float*)d_in[0];
    float* out = (float*)d_out;
    unsigned short* zb = (unsigned short*)d_ws;                       // 8192*512 bf16 = 8 MB
    float* sq = (float*)((char*)d_ws + (size_t)NROWS * KDIM * 2);     // 32 KB
    float* acc = sq + NROWS;                                          // 4 B

    prep_kernel<<<NROWS / 4, 256, 0, stream>>>(z, zb, sq, acc);
    gram_kernel<<<NBLK, 256, 0, stream>>>(zb, sq, acc);
    finish_kernel<<<1, 1, 0, stream>>>(acc, out);
}